// Round 2
// baseline (1969.918 us; speedup 1.0000x reference)
//
#include <hip/hip_runtime.h>

#define N_NODES 100000
#define N_PAD 100352          // 392 * 256
#define NBLK 392
#define IN_FEAT 128
#define OUT_FEAT 128
#define NUM_RELS 64
#define EDGES_PER_REL 16384
#define NUM_BASES 16
#define E_TOTAL (NUM_RELS * EDGES_PER_REL)

__device__ inline unsigned short f2bf(float f) {
  unsigned int u = __float_as_uint(f);
  unsigned int r = u + 0x7FFFu + ((u >> 16) & 1u);   // RNE
  return (unsigned short)(r >> 16);
}

// ---------------------------------------------------------------------------
// Kernel 1: W[r] = sum_b w_comp[r][b] * weight[b]   -> ws (64*128*128 f32)
// ---------------------------------------------------------------------------
__global__ __launch_bounds__(256) void compose_w_kernel(
    const float* __restrict__ weight, const float* __restrict__ w_comp,
    float* __restrict__ W) {
  int idx = blockIdx.x * 256 + threadIdx.x;
  int r = idx >> 14;
  int io = idx & 16383;
  const float* wc = w_comp + r * NUM_BASES;
  float acc = 0.f;
#pragma unroll
  for (int b = 0; b < NUM_BASES; ++b)
    acc += wc[b] * weight[b * (IN_FEAT * OUT_FEAT) + io];
  W[idx] = acc;
}

// ---------------------------------------------------------------------------
// Kernel 2: out[n] = h_bias + feat[n] @ loop_weight   (64 nodes / block)
// ---------------------------------------------------------------------------
__global__ __launch_bounds__(256) void init_out_kernel(
    const float* __restrict__ feat, const float* __restrict__ loop_w,
    const float* __restrict__ bias, float* __restrict__ out) {
  __shared__ float4 A4[64][32];
  int t = threadIdx.x;
  long base = (long)blockIdx.x * 64;
#pragma unroll
  for (int j = 0; j < 8; ++j) {
    int idx = t + j * 256;
    int e = idx >> 5, k4 = idx & 31;
    long n = base + e;
    float4 v = make_float4(0.f, 0.f, 0.f, 0.f);
    if (n < N_NODES) v = ((const float4*)feat)[n * 32 + k4];
    A4[e][k4] = v;
  }
  __syncthreads();
  int og = t & 31, eg = t >> 5;
  float acc[8][4];
#pragma unroll
  for (int j = 0; j < 8; ++j)
#pragma unroll
    for (int d = 0; d < 4; ++d) acc[j][d] = 0.f;

  const float4* W4 = (const float4*)loop_w;
  for (int k4 = 0; k4 < 32; ++k4) {
    float4 a[8];
#pragma unroll
    for (int j = 0; j < 8; ++j) a[j] = A4[eg * 8 + j][k4];
#pragma unroll
    for (int d = 0; d < 4; ++d) {
      float4 w = W4[(k4 * 4 + d) * 32 + og];
#pragma unroll
      for (int j = 0; j < 8; ++j) {
        float av = ((const float*)&a[j])[d];
        acc[j][0] += av * w.x;
        acc[j][1] += av * w.y;
        acc[j][2] += av * w.z;
        acc[j][3] += av * w.w;
      }
    }
  }
  float4 b = ((const float4*)bias)[og];
#pragma unroll
  for (int j = 0; j < 8; ++j) {
    long n = base + eg * 8 + j;
    if (n < N_NODES) {
      float4 v = make_float4(acc[j][0] + b.x, acc[j][1] + b.y,
                             acc[j][2] + b.z, acc[j][3] + b.w);
      ((float4*)out)[n * 32 + og] = v;
    }
  }
}

// ---------------------------------------------------------------------------
// CSR-by-dst build: zero counts, histogram, two-level scan, index scatter
// ---------------------------------------------------------------------------
__global__ __launch_bounds__(256) void zero_cnt_kernel(int* __restrict__ cnt) {
  int idx = blockIdx.x * 256 + threadIdx.x;
  cnt[idx] = 0;
}

__global__ __launch_bounds__(256) void hist_kernel(
    const int* __restrict__ dst, int* __restrict__ cnt) {
  int e = blockIdx.x * 256 + threadIdx.x;
  atomicAdd(&cnt[dst[e]], 1);
}

__global__ __launch_bounds__(256) void scan1_kernel(
    const int* __restrict__ cnt, int* __restrict__ row,
    int* __restrict__ bsum) {
  __shared__ int s[256];
  int t = threadIdx.x;
  int idx = blockIdx.x * 256 + t;
  int v = cnt[idx];
  s[t] = v;
  __syncthreads();
  for (int o = 1; o < 256; o <<= 1) {
    int x = (t >= o) ? s[t - o] : 0;
    __syncthreads();
    s[t] += x;
    __syncthreads();
  }
  row[idx] = s[t] - v;                 // exclusive within block
  if (t == 255) bsum[blockIdx.x] = s[t];
}

__global__ __launch_bounds__(512) void scan2_kernel(
    const int* __restrict__ bsum, int* __restrict__ boff) {
  __shared__ int s[512];
  int t = threadIdx.x;
  int v = (t < NBLK) ? bsum[t] : 0;
  s[t] = v;
  __syncthreads();
  for (int o = 1; o < 512; o <<= 1) {
    int x = (t >= o) ? s[t - o] : 0;
    __syncthreads();
    s[t] += x;
    __syncthreads();
  }
  if (t < NBLK) boff[t] = s[t] - v;    // exclusive block offsets
}

__global__ __launch_bounds__(256) void scan3_kernel(
    int* __restrict__ row, const int* __restrict__ boff,
    int* __restrict__ fill) {
  int idx = blockIdx.x * 256 + threadIdx.x;
  int v = row[idx] + boff[blockIdx.x];
  row[idx] = v;
  fill[idx] = v;
}

__global__ __launch_bounds__(256) void scatter_eid_kernel(
    const int* __restrict__ dst, int* __restrict__ fill,
    int* __restrict__ eid) {
  int e = blockIdx.x * 256 + threadIdx.x;
  int d = dst[e];
  int pos = atomicAdd(&fill[d], 1);
  eid[pos] = e;
}

// ---------------------------------------------------------------------------
// Phase A: msg[e] = (feat[src[e]] @ W[rel]) * norm[e]  -> bf16 scratch
// 64 edges / block; 256 blocks per relation (edges sorted by relation).
// ---------------------------------------------------------------------------
__global__ __launch_bounds__(256) void edge_gemm_kernel(
    const float* __restrict__ feat, const float* __restrict__ W,
    const float* __restrict__ norm, const int* __restrict__ src,
    unsigned short* __restrict__ msg) {
  __shared__ float4 A4[64][32];
  __shared__ int s_src[64];
  __shared__ float s_norm[64];
  int t = threadIdx.x;
  long base = (long)blockIdx.x * 64;
  int rel = blockIdx.x >> 8;
  const float4* Wr4 = (const float4*)(W + (long)rel * IN_FEAT * OUT_FEAT);

  if (t < 64) {
    s_src[t] = src[base + t];
    s_norm[t] = norm[base + t];
  }
  __syncthreads();
#pragma unroll
  for (int j = 0; j < 8; ++j) {
    int idx = t + j * 256;
    int e = idx >> 5, k4 = idx & 31;
    A4[e][k4] = ((const float4*)feat)[(long)s_src[e] * 32 + k4];
  }
  __syncthreads();

  int og = t & 31, eg = t >> 5;
  float acc[8][4];
#pragma unroll
  for (int j = 0; j < 8; ++j)
#pragma unroll
    for (int d = 0; d < 4; ++d) acc[j][d] = 0.f;

  for (int k4 = 0; k4 < 32; ++k4) {
    float4 a[8];
#pragma unroll
    for (int j = 0; j < 8; ++j) a[j] = A4[eg * 8 + j][k4];
#pragma unroll
    for (int d = 0; d < 4; ++d) {
      float4 w = Wr4[(k4 * 4 + d) * 32 + og];
#pragma unroll
      for (int j = 0; j < 8; ++j) {
        float av = ((const float*)&a[j])[d];
        acc[j][0] += av * w.x;
        acc[j][1] += av * w.y;
        acc[j][2] += av * w.z;
        acc[j][3] += av * w.w;
      }
    }
  }

#pragma unroll
  for (int j = 0; j < 8; ++j) {
    int e = eg * 8 + j;
    float nm = s_norm[e];
    ushort4 p;
    p.x = f2bf(acc[j][0] * nm);
    p.y = f2bf(acc[j][1] * nm);
    p.z = f2bf(acc[j][2] * nm);
    p.w = f2bf(acc[j][3] * nm);
    ((ushort4*)msg)[(base + e) * 32 + og] = p;
  }
}

// ---------------------------------------------------------------------------
// Phase B: out[n] = relu(out[n] + sum_{e: dst[e]==n} msg[e])
// One wave per node (4 nodes / block); lane handles 2 consecutive floats.
// ---------------------------------------------------------------------------
__global__ __launch_bounds__(256) void gather_kernel(
    const unsigned short* __restrict__ msg, const int* __restrict__ row,
    const int* __restrict__ eid, float* __restrict__ out) {
  int wave = threadIdx.x >> 6, lane = threadIdx.x & 63;
  int n = blockIdx.x * 4 + wave;
  if (n >= N_NODES) return;
  int beg = row[n], end = row[n + 1];
  float ax = 0.f, ay = 0.f;
  for (int j = beg; j < end; ++j) {
    int e = eid[j];
    unsigned int m = *(const unsigned int*)(msg + ((long)e << 7) + lane * 2);
    ax += __uint_as_float(m << 16);          // low bf16
    ay += __uint_as_float(m & 0xFFFF0000u);  // high bf16
  }
  float2 o = ((float2*)out)[(long)n * 64 + lane];
  o.x = fmaxf(o.x + ax, 0.f);
  o.y = fmaxf(o.y + ay, 0.f);
  ((float2*)out)[(long)n * 64 + lane] = o;
}

// ---------------------------------------------------------------------------
// Fallback path (small ws): round-1 atomic scatter + relu
// ---------------------------------------------------------------------------
__global__ __launch_bounds__(256) void edge_msg_atomic_kernel(
    const float* __restrict__ feat, const float* __restrict__ W,
    const float* __restrict__ norm, const int* __restrict__ src,
    const int* __restrict__ dst, float* __restrict__ out) {
  __shared__ float4 A4[64][32];
  __shared__ int s_src[64];
  __shared__ int s_dst[64];
  __shared__ float s_norm[64];
  int t = threadIdx.x;
  long base = (long)blockIdx.x * 64;
  int rel = blockIdx.x >> 8;
  const float4* Wr4 = (const float4*)(W + (long)rel * IN_FEAT * OUT_FEAT);

  if (t < 64) {
    s_src[t] = src[base + t];
    s_dst[t] = dst[base + t];
    s_norm[t] = norm[base + t];
  }
  __syncthreads();
#pragma unroll
  for (int j = 0; j < 8; ++j) {
    int idx = t + j * 256;
    int e = idx >> 5, k4 = idx & 31;
    A4[e][k4] = ((const float4*)feat)[(long)s_src[e] * 32 + k4];
  }
  __syncthreads();

  int og = t & 31, eg = t >> 5;
  float acc[8][4];
#pragma unroll
  for (int j = 0; j < 8; ++j)
#pragma unroll
    for (int d = 0; d < 4; ++d) acc[j][d] = 0.f;

  for (int k4 = 0; k4 < 32; ++k4) {
    float4 a[8];
#pragma unroll
    for (int j = 0; j < 8; ++j) a[j] = A4[eg * 8 + j][k4];
#pragma unroll
    for (int d = 0; d < 4; ++d) {
      float4 w = Wr4[(k4 * 4 + d) * 32 + og];
#pragma unroll
      for (int j = 0; j < 8; ++j) {
        float av = ((const float*)&a[j])[d];
        acc[j][0] += av * w.x;
        acc[j][1] += av * w.y;
        acc[j][2] += av * w.z;
        acc[j][3] += av * w.w;
      }
    }
  }
#pragma unroll
  for (int j = 0; j < 8; ++j) {
    int e = eg * 8 + j;
    float nm = s_norm[e];
    float* orow = out + (long)s_dst[e] * OUT_FEAT + og * 4;
#pragma unroll
    for (int d = 0; d < 4; ++d) atomicAdd(orow + d, acc[j][d] * nm);
  }
}

__global__ __launch_bounds__(256) void relu_kernel(float* __restrict__ out) {
  int idx = blockIdx.x * 256 + threadIdx.x;
  float4 v = ((const float4*)out)[idx];
  v.x = fmaxf(v.x, 0.f);
  v.y = fmaxf(v.y, 0.f);
  v.z = fmaxf(v.z, 0.f);
  v.w = fmaxf(v.w, 0.f);
  ((float4*)out)[idx] = v;
}

extern "C" void kernel_launch(void* const* d_in, const int* in_sizes, int n_in,
                              void* d_out, int out_size, void* d_ws, size_t ws_size,
                              hipStream_t stream) {
  const float* feat   = (const float*)d_in[0];
  const float* weight = (const float*)d_in[1];
  const float* w_comp = (const float*)d_in[2];
  const float* h_bias = (const float*)d_in[3];
  const float* loop_w = (const float*)d_in[4];
  const float* norm   = (const float*)d_in[5];
  const int*   src    = (const int*)d_in[6];
  const int*   dst    = (const int*)d_in[7];
  float* out = (float*)d_out;

  // ws layout
  char* p = (char*)d_ws;
  const size_t SZ_W    = (size_t)NUM_RELS * IN_FEAT * OUT_FEAT * 4;   //   4 MB
  const size_t SZ_MSG  = (size_t)E_TOTAL * OUT_FEAT * 2;              // 268 MB
  const size_t SZ_CNT  = (size_t)N_PAD * 4;
  const size_t SZ_BS   = 2048;
  const size_t SZ_EID  = (size_t)E_TOTAL * 4;
  const size_t NEED = SZ_W + SZ_MSG + 3 * SZ_CNT + 2 * SZ_BS + SZ_EID;

  float* W = (float*)p;                       p += SZ_W;

  hipLaunchKernelGGL(compose_w_kernel, dim3((NUM_RELS * IN_FEAT * OUT_FEAT) / 256),
                     dim3(256), 0, stream, weight, w_comp, W);
  hipLaunchKernelGGL(init_out_kernel, dim3((N_NODES + 63) / 64),
                     dim3(256), 0, stream, feat, loop_w, h_bias, out);

  if (ws_size >= NEED) {
    unsigned short* msg = (unsigned short*)p;  p += SZ_MSG;
    int* cnt  = (int*)p;                       p += SZ_CNT;
    int* row  = (int*)p;                       p += SZ_CNT;
    int* fill = (int*)p;                       p += SZ_CNT;
    int* bsum = (int*)p;                       p += SZ_BS;
    int* boff = (int*)p;                       p += SZ_BS;
    int* eid  = (int*)p;                       p += SZ_EID;

    hipLaunchKernelGGL(zero_cnt_kernel, dim3(NBLK), dim3(256), 0, stream, cnt);
    hipLaunchKernelGGL(hist_kernel, dim3(E_TOTAL / 256), dim3(256), 0, stream,
                       dst, cnt);
    hipLaunchKernelGGL(scan1_kernel, dim3(NBLK), dim3(256), 0, stream,
                       cnt, row, bsum);
    hipLaunchKernelGGL(scan2_kernel, dim3(1), dim3(512), 0, stream, bsum, boff);
    hipLaunchKernelGGL(scan3_kernel, dim3(NBLK), dim3(256), 0, stream,
                       row, boff, fill);
    hipLaunchKernelGGL(edge_gemm_kernel, dim3(E_TOTAL / 64), dim3(256), 0, stream,
                       feat, W, norm, src, msg);
    hipLaunchKernelGGL(scatter_eid_kernel, dim3(E_TOTAL / 256), dim3(256), 0,
                       stream, dst, fill, eid);
    hipLaunchKernelGGL(gather_kernel, dim3((N_NODES + 3) / 4), dim3(256), 0,
                       stream, msg, row, eid, out);
  } else {
    hipLaunchKernelGGL(edge_msg_atomic_kernel, dim3(E_TOTAL / 64), dim3(256), 0,
                       stream, feat, W, norm, src, dst, out);
    hipLaunchKernelGGL(relu_kernel, dim3((N_NODES * OUT_FEAT / 4) / 256),
                       dim3(256), 0, stream, out);
  }
}

// Round 3
// 1326.369 us; speedup vs baseline: 1.4852x; 1.4852x over previous
//
#include <hip/hip_runtime.h>

#define N_NODES 100000
#define N_PAD 100352          // 392 * 256
#define NBLK 392
#define IN_FEAT 128
#define OUT_FEAT 128
#define NUM_RELS 64
#define EDGES_PER_REL 16384
#define NUM_BASES 16
#define E_TOTAL (NUM_RELS * EDGES_PER_REL)

__device__ inline unsigned short f2bf(float f) {
  unsigned int u = __float_as_uint(f);
  unsigned int r = u + 0x7FFFu + ((u >> 16) & 1u);   // RNE
  return (unsigned short)(r >> 16);
}

// ---------------------------------------------------------------------------
// Kernel 1: W[r] = sum_b w_comp[r][b] * weight[b]   -> ws (64*128*128 f32)
// ---------------------------------------------------------------------------
__global__ __launch_bounds__(256) void compose_w_kernel(
    const float* __restrict__ weight, const float* __restrict__ w_comp,
    float* __restrict__ W) {
  int idx = blockIdx.x * 256 + threadIdx.x;
  int r = idx >> 14;
  int io = idx & 16383;
  const float* wc = w_comp + r * NUM_BASES;
  float acc = 0.f;
#pragma unroll
  for (int b = 0; b < NUM_BASES; ++b)
    acc += wc[b] * weight[b * (IN_FEAT * OUT_FEAT) + io];
  W[idx] = acc;
}

// ---------------------------------------------------------------------------
// Kernel 2: out[n] = h_bias + feat[n] @ loop_weight   (64 nodes / block)
// ---------------------------------------------------------------------------
__global__ __launch_bounds__(256) void init_out_kernel(
    const float* __restrict__ feat, const float* __restrict__ loop_w,
    const float* __restrict__ bias, float* __restrict__ out) {
  __shared__ float4 A4[64][32];
  int t = threadIdx.x;
  long base = (long)blockIdx.x * 64;
#pragma unroll
  for (int j = 0; j < 8; ++j) {
    int idx = t + j * 256;
    int e = idx >> 5, k4 = idx & 31;
    long n = base + e;
    float4 v = make_float4(0.f, 0.f, 0.f, 0.f);
    if (n < N_NODES) v = ((const float4*)feat)[n * 32 + k4];
    A4[e][k4] = v;
  }
  __syncthreads();
  int og = t & 31, eg = t >> 5;
  float acc[8][4];
#pragma unroll
  for (int j = 0; j < 8; ++j)
#pragma unroll
    for (int d = 0; d < 4; ++d) acc[j][d] = 0.f;

  const float4* W4 = (const float4*)loop_w;
  for (int k4 = 0; k4 < 32; ++k4) {
    float4 a[8];
#pragma unroll
    for (int j = 0; j < 8; ++j) a[j] = A4[eg * 8 + j][k4];
#pragma unroll
    for (int d = 0; d < 4; ++d) {
      float4 w = W4[(k4 * 4 + d) * 32 + og];
#pragma unroll
      for (int j = 0; j < 8; ++j) {
        float av = ((const float*)&a[j])[d];
        acc[j][0] += av * w.x;
        acc[j][1] += av * w.y;
        acc[j][2] += av * w.z;
        acc[j][3] += av * w.w;
      }
    }
  }
  float4 b = ((const float4*)bias)[og];
#pragma unroll
  for (int j = 0; j < 8; ++j) {
    long n = base + eg * 8 + j;
    if (n < N_NODES) {
      float4 v = make_float4(acc[j][0] + b.x, acc[j][1] + b.y,
                             acc[j][2] + b.z, acc[j][3] + b.w);
      ((float4*)out)[n * 32 + og] = v;
    }
  }
}

// ---------------------------------------------------------------------------
// CSR-by-dst build: zero counts, histogram, two-level scan, index scatter
// ---------------------------------------------------------------------------
__global__ __launch_bounds__(256) void zero_cnt_kernel(int* __restrict__ cnt) {
  int idx = blockIdx.x * 256 + threadIdx.x;
  cnt[idx] = 0;
}

__global__ __launch_bounds__(256) void hist_kernel(
    const int* __restrict__ dst, int* __restrict__ cnt) {
  int e = blockIdx.x * 256 + threadIdx.x;
  atomicAdd(&cnt[dst[e]], 1);
}

__global__ __launch_bounds__(256) void scan1_kernel(
    const int* __restrict__ cnt, int* __restrict__ row,
    int* __restrict__ bsum) {
  __shared__ int s[256];
  int t = threadIdx.x;
  int idx = blockIdx.x * 256 + t;
  int v = cnt[idx];
  s[t] = v;
  __syncthreads();
  for (int o = 1; o < 256; o <<= 1) {
    int x = (t >= o) ? s[t - o] : 0;
    __syncthreads();
    s[t] += x;
    __syncthreads();
  }
  row[idx] = s[t] - v;                 // exclusive within block
  if (t == 255) bsum[blockIdx.x] = s[t];
}

__global__ __launch_bounds__(512) void scan2_kernel(
    const int* __restrict__ bsum, int* __restrict__ boff) {
  __shared__ int s[512];
  int t = threadIdx.x;
  int v = (t < NBLK) ? bsum[t] : 0;
  s[t] = v;
  __syncthreads();
  for (int o = 1; o < 512; o <<= 1) {
    int x = (t >= o) ? s[t - o] : 0;
    __syncthreads();
    s[t] += x;
    __syncthreads();
  }
  if (t < NBLK) boff[t] = s[t] - v;    // exclusive block offsets
}

__global__ __launch_bounds__(256) void scan3_kernel(
    int* __restrict__ row, const int* __restrict__ boff,
    int* __restrict__ fill) {
  int idx = blockIdx.x * 256 + threadIdx.x;
  int v = row[idx] + boff[blockIdx.x];
  row[idx] = v;
  fill[idx] = v;
}

__global__ __launch_bounds__(256) void scatter_eid_kernel(
    const int* __restrict__ dst, int* __restrict__ fill,
    int* __restrict__ eid) {
  int e = blockIdx.x * 256 + threadIdx.x;
  int d = dst[e];
  int pos = atomicAdd(&fill[d], 1);
  eid[pos] = e;
}

// ---------------------------------------------------------------------------
// Phase A (chunked): msg[e - e_lo] = (feat[src[e]] @ W[rel]) * norm[e] (bf16)
// 64 edges / block; rel derived from global edge index (16384 edges / rel).
// ---------------------------------------------------------------------------
__global__ __launch_bounds__(256) void edge_gemm_kernel(
    const float* __restrict__ feat, const float* __restrict__ W,
    const float* __restrict__ norm, const int* __restrict__ src,
    unsigned short* __restrict__ msg, int e_lo) {
  __shared__ float4 A4[64][32];
  __shared__ int s_src[64];
  __shared__ float s_norm[64];
  int t = threadIdx.x;
  long lbase = (long)blockIdx.x * 64;        // local (chunk) edge base
  long base = (long)e_lo + lbase;            // global edge base
  int rel = (int)(base >> 14);
  const float4* Wr4 = (const float4*)(W + (long)rel * IN_FEAT * OUT_FEAT);

  if (t < 64) {
    s_src[t] = src[base + t];
    s_norm[t] = norm[base + t];
  }
  __syncthreads();
#pragma unroll
  for (int j = 0; j < 8; ++j) {
    int idx = t + j * 256;
    int e = idx >> 5, k4 = idx & 31;
    A4[e][k4] = ((const float4*)feat)[(long)s_src[e] * 32 + k4];
  }
  __syncthreads();

  int og = t & 31, eg = t >> 5;
  float acc[8][4];
#pragma unroll
  for (int j = 0; j < 8; ++j)
#pragma unroll
    for (int d = 0; d < 4; ++d) acc[j][d] = 0.f;

  for (int k4 = 0; k4 < 32; ++k4) {
    float4 a[8];
#pragma unroll
    for (int j = 0; j < 8; ++j) a[j] = A4[eg * 8 + j][k4];
#pragma unroll
    for (int d = 0; d < 4; ++d) {
      float4 w = Wr4[(k4 * 4 + d) * 32 + og];
#pragma unroll
      for (int j = 0; j < 8; ++j) {
        float av = ((const float*)&a[j])[d];
        acc[j][0] += av * w.x;
        acc[j][1] += av * w.y;
        acc[j][2] += av * w.z;
        acc[j][3] += av * w.w;
      }
    }
  }

#pragma unroll
  for (int j = 0; j < 8; ++j) {
    int e = eg * 8 + j;
    float nm = s_norm[e];
    ushort4 p;
    p.x = f2bf(acc[j][0] * nm);
    p.y = f2bf(acc[j][1] * nm);
    p.z = f2bf(acc[j][2] * nm);
    p.w = f2bf(acc[j][3] * nm);
    ((ushort4*)msg)[(lbase + e) * 32 + og] = p;
  }
}

// ---------------------------------------------------------------------------
// Phase B (chunked): out[n] += sum_{e: dst[e]==n, e in [e_lo,e_hi)} msg[e-e_lo]
// One wave per node; lane handles 2 consecutive floats. Last chunk fuses ReLU.
// ---------------------------------------------------------------------------
__global__ __launch_bounds__(256) void gather_kernel(
    const unsigned short* __restrict__ msg, const int* __restrict__ row,
    const int* __restrict__ eid, float* __restrict__ out,
    int e_lo, int e_hi, int do_relu) {
  int wave = threadIdx.x >> 6, lane = threadIdx.x & 63;
  int n = blockIdx.x * 4 + wave;
  if (n >= N_NODES) return;
  int beg = row[n], end = row[n + 1];
  float ax = 0.f, ay = 0.f;
  bool hit = false;
  for (int j = beg; j < end; ++j) {
    int e = eid[j];                          // wave-uniform broadcast load
    if (e >= e_lo && e < e_hi) {
      hit = true;
      unsigned int m =
          *(const unsigned int*)(msg + ((long)(e - e_lo) << 7) + lane * 2);
      ax += __uint_as_float(m << 16);          // low bf16
      ay += __uint_as_float(m & 0xFFFF0000u);  // high bf16
    }
  }
  if (do_relu) {
    float2 o = ((float2*)out)[(long)n * 64 + lane];
    o.x = fmaxf(o.x + ax, 0.f);
    o.y = fmaxf(o.y + ay, 0.f);
    ((float2*)out)[(long)n * 64 + lane] = o;
  } else if (hit) {
    float2 o = ((float2*)out)[(long)n * 64 + lane];
    o.x += ax;
    o.y += ay;
    ((float2*)out)[(long)n * 64 + lane] = o;
  }
}

// ---------------------------------------------------------------------------
// Fallback path (tiny ws): atomic scatter + relu
// ---------------------------------------------------------------------------
__global__ __launch_bounds__(256) void edge_msg_atomic_kernel(
    const float* __restrict__ feat, const float* __restrict__ W,
    const float* __restrict__ norm, const int* __restrict__ src,
    const int* __restrict__ dst, float* __restrict__ out) {
  __shared__ float4 A4[64][32];
  __shared__ int s_src[64];
  __shared__ int s_dst[64];
  __shared__ float s_norm[64];
  int t = threadIdx.x;
  long base = (long)blockIdx.x * 64;
  int rel = blockIdx.x >> 8;
  const float4* Wr4 = (const float4*)(W + (long)rel * IN_FEAT * OUT_FEAT);

  if (t < 64) {
    s_src[t] = src[base + t];
    s_dst[t] = dst[base + t];
    s_norm[t] = norm[base + t];
  }
  __syncthreads();
#pragma unroll
  for (int j = 0; j < 8; ++j) {
    int idx = t + j * 256;
    int e = idx >> 5, k4 = idx & 31;
    A4[e][k4] = ((const float4*)feat)[(long)s_src[e] * 32 + k4];
  }
  __syncthreads();

  int og = t & 31, eg = t >> 5;
  float acc[8][4];
#pragma unroll
  for (int j = 0; j < 8; ++j)
#pragma unroll
    for (int d = 0; d < 4; ++d) acc[j][d] = 0.f;

  for (int k4 = 0; k4 < 32; ++k4) {
    float4 a[8];
#pragma unroll
    for (int j = 0; j < 8; ++j) a[j] = A4[eg * 8 + j][k4];
#pragma unroll
    for (int d = 0; d < 4; ++d) {
      float4 w = Wr4[(k4 * 4 + d) * 32 + og];
#pragma unroll
      for (int j = 0; j < 8; ++j) {
        float av = ((const float*)&a[j])[d];
        acc[j][0] += av * w.x;
        acc[j][1] += av * w.y;
        acc[j][2] += av * w.z;
        acc[j][3] += av * w.w;
      }
    }
  }
#pragma unroll
  for (int j = 0; j < 8; ++j) {
    int e = eg * 8 + j;
    float nm = s_norm[e];
    float* orow = out + (long)s_dst[e] * OUT_FEAT + og * 4;
#pragma unroll
    for (int d = 0; d < 4; ++d) atomicAdd(orow + d, acc[j][d] * nm);
  }
}

__global__ __launch_bounds__(256) void relu_kernel(float* __restrict__ out) {
  int idx = blockIdx.x * 256 + threadIdx.x;
  float4 v = ((const float4*)out)[idx];
  v.x = fmaxf(v.x, 0.f);
  v.y = fmaxf(v.y, 0.f);
  v.z = fmaxf(v.z, 0.f);
  v.w = fmaxf(v.w, 0.f);
  ((float4*)out)[idx] = v;
}

extern "C" void kernel_launch(void* const* d_in, const int* in_sizes, int n_in,
                              void* d_out, int out_size, void* d_ws, size_t ws_size,
                              hipStream_t stream) {
  const float* feat   = (const float*)d_in[0];
  const float* weight = (const float*)d_in[1];
  const float* w_comp = (const float*)d_in[2];
  const float* h_bias = (const float*)d_in[3];
  const float* loop_w = (const float*)d_in[4];
  const float* norm   = (const float*)d_in[5];
  const int*   src    = (const int*)d_in[6];
  const int*   dst    = (const int*)d_in[7];
  float* out = (float*)d_out;

  // ws layout: fixed structures first, variable-size msg chunk last.
  const size_t SZ_W   = (size_t)NUM_RELS * IN_FEAT * OUT_FEAT * 4;  // 4 MB
  const size_t SZ_CNT = (size_t)N_PAD * 4;                          // 0.4 MB
  const size_t SZ_BS  = 2048;
  const size_t SZ_EID = (size_t)E_TOTAL * 4;                        // 4.2 MB
  const size_t FIXED  = SZ_W + 3 * SZ_CNT + 2 * SZ_BS + SZ_EID;     // ~9.6 MB

  // pick largest chunk (in relations) whose msg buffer fits
  int CH = 0;
  {
    const size_t per_rel = (size_t)EDGES_PER_REL * OUT_FEAT * 2;    // 4.19 MB
    if (ws_size >= FIXED + 64 * per_rel)      CH = 64;   // ~278 MB
    else if (ws_size >= FIXED + 8 * per_rel)  CH = 8;    // ~43 MB
    else if (ws_size >= FIXED + 1 * per_rel)  CH = 1;    // ~14 MB
  }

  char* p = (char*)d_ws;
  float* W   = (float*)p;          p += SZ_W;
  int* cnt   = (int*)p;            p += SZ_CNT;
  int* row   = (int*)p;            p += SZ_CNT;
  int* fill  = (int*)p;            p += SZ_CNT;
  int* bsum  = (int*)p;            p += SZ_BS;
  int* boff  = (int*)p;            p += SZ_BS;
  int* eid   = (int*)p;            p += SZ_EID;
  unsigned short* msg = (unsigned short*)p;

  hipLaunchKernelGGL(compose_w_kernel, dim3((NUM_RELS * IN_FEAT * OUT_FEAT) / 256),
                     dim3(256), 0, stream, weight, w_comp, W);
  hipLaunchKernelGGL(init_out_kernel, dim3((N_NODES + 63) / 64),
                     dim3(256), 0, stream, feat, loop_w, h_bias, out);

  if (CH > 0) {
    // CSR-by-dst build
    hipLaunchKernelGGL(zero_cnt_kernel, dim3(NBLK), dim3(256), 0, stream, cnt);
    hipLaunchKernelGGL(hist_kernel, dim3(E_TOTAL / 256), dim3(256), 0, stream,
                       dst, cnt);
    hipLaunchKernelGGL(scan1_kernel, dim3(NBLK), dim3(256), 0, stream,
                       cnt, row, bsum);
    hipLaunchKernelGGL(scan2_kernel, dim3(1), dim3(512), 0, stream, bsum, boff);
    hipLaunchKernelGGL(scan3_kernel, dim3(NBLK), dim3(256), 0, stream,
                       row, boff, fill);
    hipLaunchKernelGGL(scatter_eid_kernel, dim3(E_TOTAL / 256), dim3(256), 0,
                       stream, dst, fill, eid);

    const int n_chunks = NUM_RELS / CH;
    const int chunk_edges = CH * EDGES_PER_REL;
    for (int c = 0; c < n_chunks; ++c) {
      int e_lo = c * chunk_edges;
      int e_hi = e_lo + chunk_edges;
      hipLaunchKernelGGL(edge_gemm_kernel, dim3(chunk_edges / 64), dim3(256), 0,
                         stream, feat, W, norm, src, msg, e_lo);
      hipLaunchKernelGGL(gather_kernel, dim3((N_NODES + 3) / 4), dim3(256), 0,
                         stream, msg, row, eid, out, e_lo, e_hi,
                         (c == n_chunks - 1) ? 1 : 0);
    }
  } else {
    hipLaunchKernelGGL(edge_msg_atomic_kernel, dim3(E_TOTAL / 64), dim3(256), 0,
                       stream, feat, W, norm, src, dst, out);
    hipLaunchKernelGGL(relu_kernel, dim3((N_NODES * OUT_FEAT / 4) / 256),
                       dim3(256), 0, stream, out);
  }
}

// Round 4
// 517.532 us; speedup vs baseline: 3.8064x; 2.5629x over previous
//
#include <hip/hip_runtime.h>

#define N_NODES 100000
#define N_PAD 100352          // 392 * 256
#define NBLK 392
#define IN_FEAT 128
#define OUT_FEAT 128
#define NUM_RELS 64
#define EDGES_PER_REL 16384
#define NUM_BASES 16
#define E_TOTAL (NUM_RELS * EDGES_PER_REL)

typedef __bf16 bf16x8 __attribute__((ext_vector_type(8)));
typedef float floatx4 __attribute__((ext_vector_type(4)));

__device__ inline unsigned short f2bf(float f) {
  unsigned int u = __float_as_uint(f);
  unsigned int r = u + 0x7FFFu + ((u >> 16) & 1u);   // RNE
  return (unsigned short)(r >> 16);
}

// ---------------------------------------------------------------------------
// Kernel 1: W[r] = sum_b w_comp[r][b] * weight[b]  -> bf16, k-packed layout
// Wp[r][kp][n][j] where k = kp*8 + j  (fragment-ready 16B rows)
// ---------------------------------------------------------------------------
__global__ __launch_bounds__(256) void compose_w_bf16_kernel(
    const float* __restrict__ weight, const float* __restrict__ w_comp,
    unsigned short* __restrict__ Wp) {
  int idx = blockIdx.x * 256 + threadIdx.x;     // 64*16384
  int r = idx >> 14;
  int off = idx & 16383;                        // kp*1024 + n*8 + j
  int j = off & 7, n = (off >> 3) & 127, kp = off >> 10;
  int k = kp * 8 + j;
  const float* wc = w_comp + r * NUM_BASES;
  float acc = 0.f;
#pragma unroll
  for (int b = 0; b < NUM_BASES; ++b)
    acc += wc[b] * weight[b * 16384 + k * 128 + n];
  Wp[idx] = f2bf(acc);
}

// fp32 W for the atomic fallback path
__global__ __launch_bounds__(256) void compose_w_f32_kernel(
    const float* __restrict__ weight, const float* __restrict__ w_comp,
    float* __restrict__ W) {
  int idx = blockIdx.x * 256 + threadIdx.x;
  int r = idx >> 14;
  int io = idx & 16383;
  const float* wc = w_comp + r * NUM_BASES;
  float acc = 0.f;
#pragma unroll
  for (int b = 0; b < NUM_BASES; ++b)
    acc += wc[b] * weight[b * 16384 + io];
  W[idx] = acc;
}

// ---------------------------------------------------------------------------
// Kernel 2: out[n] = h_bias + feat[n] @ loop_weight   (fp32 vector, 64/block)
// ---------------------------------------------------------------------------
__global__ __launch_bounds__(256) void init_out_kernel(
    const float* __restrict__ feat, const float* __restrict__ loop_w,
    const float* __restrict__ bias, float* __restrict__ out) {
  __shared__ float4 A4[64][32];
  int t = threadIdx.x;
  long base = (long)blockIdx.x * 64;
#pragma unroll
  for (int j = 0; j < 8; ++j) {
    int idx = t + j * 256;
    int e = idx >> 5, k4 = idx & 31;
    long n = base + e;
    float4 v = make_float4(0.f, 0.f, 0.f, 0.f);
    if (n < N_NODES) v = ((const float4*)feat)[n * 32 + k4];
    A4[e][k4] = v;
  }
  __syncthreads();
  int og = t & 31, eg = t >> 5;
  float acc[8][4];
#pragma unroll
  for (int j = 0; j < 8; ++j)
#pragma unroll
    for (int d = 0; d < 4; ++d) acc[j][d] = 0.f;

  const float4* W4 = (const float4*)loop_w;
  for (int k4 = 0; k4 < 32; ++k4) {
    float4 a[8];
#pragma unroll
    for (int j = 0; j < 8; ++j) a[j] = A4[eg * 8 + j][k4];
#pragma unroll
    for (int d = 0; d < 4; ++d) {
      float4 w = W4[(k4 * 4 + d) * 32 + og];
#pragma unroll
      for (int j = 0; j < 8; ++j) {
        float av = ((const float*)&a[j])[d];
        acc[j][0] += av * w.x;
        acc[j][1] += av * w.y;
        acc[j][2] += av * w.z;
        acc[j][3] += av * w.w;
      }
    }
  }
  float4 b = ((const float4*)bias)[og];
#pragma unroll
  for (int j = 0; j < 8; ++j) {
    long n = base + eg * 8 + j;
    if (n < N_NODES) {
      float4 v = make_float4(acc[j][0] + b.x, acc[j][1] + b.y,
                             acc[j][2] + b.z, acc[j][3] + b.w);
      ((float4*)out)[n * 32 + og] = v;
    }
  }
}

// ---------------------------------------------------------------------------
// Per-chunk CSR build (all chunks in one pass set)
// ---------------------------------------------------------------------------
__global__ __launch_bounds__(256) void zero_kernel(int* __restrict__ p) {
  p[blockIdx.x * 256 + threadIdx.x] = 0;
}

__global__ __launch_bounds__(256) void hist8_kernel(
    const int* __restrict__ dst, int* __restrict__ cnt8, int cshift) {
  int e = blockIdx.x * 256 + threadIdx.x;
  int c = e >> cshift;
  atomicAdd(&cnt8[c * N_PAD + dst[e]], 1);
}

__global__ __launch_bounds__(256) void scan1_kernel(
    const int* __restrict__ cnt, int* __restrict__ row,
    int* __restrict__ bsum) {
  __shared__ int s[256];
  int t = threadIdx.x;
  int idx = blockIdx.x * 256 + t;
  int v = cnt[idx];
  s[t] = v;
  __syncthreads();
  for (int o = 1; o < 256; o <<= 1) {
    int x = (t >= o) ? s[t - o] : 0;
    __syncthreads();
    s[t] += x;
    __syncthreads();
  }
  row[idx] = s[t] - v;
  if (t == 255) bsum[blockIdx.x] = s[t];
}

__global__ __launch_bounds__(512) void scan2_kernel(
    const int* __restrict__ bsum, int* __restrict__ boff) {
  __shared__ int s[512];
  int t = threadIdx.x;
  int v = (t < NBLK) ? bsum[blockIdx.x * NBLK + t] : 0;
  s[t] = v;
  __syncthreads();
  for (int o = 1; o < 512; o <<= 1) {
    int x = (t >= o) ? s[t - o] : 0;
    __syncthreads();
    s[t] += x;
    __syncthreads();
  }
  if (t < NBLK) boff[blockIdx.x * NBLK + t] = s[t] - v;
}

__global__ __launch_bounds__(256) void scan3_kernel(
    int* __restrict__ row, const int* __restrict__ boff,
    int* __restrict__ fill) {
  int idx = blockIdx.x * 256 + threadIdx.x;
  int v = row[idx] + boff[blockIdx.x];
  row[idx] = v;
  fill[idx] = v;
}

// pos[e] = chunk-local CSR slot of edge e (coalesced write; no eid scatter)
__global__ __launch_bounds__(256) void scatter_pos_kernel(
    const int* __restrict__ dst, int* __restrict__ fill8,
    int* __restrict__ pos, int cshift) {
  int e = blockIdx.x * 256 + threadIdx.x;
  int c = e >> cshift;
  pos[e] = atomicAdd(&fill8[c * N_PAD + dst[e]], 1);
}

// ---------------------------------------------------------------------------
// Phase A (MFMA): msg[pos[e]] = bf16((feat[src[e]] @ W[rel]) * norm[e])
// 64 edges/block, 4 waves; wave handles 16 edges x 128 outs, K=128.
// ---------------------------------------------------------------------------
__global__ __launch_bounds__(256) void edge_gemm_mfma(
    const float* __restrict__ feat, const unsigned short* __restrict__ Wp,
    const float* __restrict__ norm, const int* __restrict__ src,
    const int* __restrict__ pos, unsigned short* __restrict__ msg, int e_lo) {
  __shared__ unsigned short A_lds[64 * 136];   // +16B row pad: 2-way banks
  __shared__ int s_src[64];
  __shared__ int s_pos[64];
  __shared__ float s_norm[64];
  int t = threadIdx.x;
  long base = (long)e_lo + (long)blockIdx.x * 64;
  int rel = (int)(base >> 14);                 // 16384 edges per relation
  const unsigned short* Wr = Wp + (long)rel * (IN_FEAT * OUT_FEAT);

  if (t < 64) {
    s_src[t] = src[base + t];
    s_pos[t] = pos[base + t];
    s_norm[t] = norm[base + t];
  }
  __syncthreads();
#pragma unroll
  for (int j = 0; j < 8; ++j) {
    int idx = t + j * 256;
    int e = idx >> 5, k4 = idx & 31;
    float4 v = ((const float4*)feat)[(long)s_src[e] * 32 + k4];
    ushort4 u;
    u.x = f2bf(v.x); u.y = f2bf(v.y); u.z = f2bf(v.z); u.w = f2bf(v.w);
    *(ushort4*)&A_lds[e * 136 + k4 * 4] = u;
  }
  __syncthreads();

  int wave = t >> 6, lane = t & 63;
  int m16 = lane & 15, quad = lane >> 4;
  floatx4 acc[8];
#pragma unroll
  for (int nt = 0; nt < 8; ++nt) acc[nt] = (floatx4){0.f, 0.f, 0.f, 0.f};

  const unsigned short* a_base = &A_lds[(wave * 16 + m16) * 136 + quad * 8];
#pragma unroll
  for (int ks = 0; ks < 4; ++ks) {
    bf16x8 a = *(const bf16x8*)(a_base + ks * 32);   // A[m][k=ks*32+quad*8..]
    int kp = ks * 4 + quad;
#pragma unroll
    for (int nt = 0; nt < 8; ++nt) {
      bf16x8 b = *(const bf16x8*)(Wr + (kp * 128 + nt * 16 + m16) * 8);
      acc[nt] = __builtin_amdgcn_mfma_f32_16x16x32_bf16(a, b, acc[nt], 0, 0, 0);
    }
  }

  // D: col = lane&15, row = quad*4 + r  -> scale by norm, write CSR slot
#pragma unroll
  for (int r = 0; r < 4; ++r) {
    int erow = wave * 16 + quad * 4 + r;
    float nm = s_norm[erow];
    long mrow = (long)s_pos[erow] * 128;
#pragma unroll
    for (int nt = 0; nt < 8; ++nt)
      msg[mrow + nt * 16 + m16] = f2bf(acc[nt][r] * nm);
  }
}

// ---------------------------------------------------------------------------
// Phase B: contiguous CSR gather. One wave per node; lane = 2 consecutive
// floats. Skips nodes with no edges in chunk; last chunk fuses ReLU.
// ---------------------------------------------------------------------------
__global__ __launch_bounds__(256) void gather_csr_kernel(
    const unsigned short* __restrict__ msg, const int* __restrict__ rowc,
    float* __restrict__ out, int do_relu) {
  int wave = threadIdx.x >> 6, lane = threadIdx.x & 63;
  int n = blockIdx.x * 4 + wave;
  if (n >= N_NODES) return;
  int beg = rowc[n], end = rowc[n + 1];
  if (!do_relu && beg == end) return;
  float ax = 0.f, ay = 0.f;
  for (int j = beg; j < end; ++j) {
    unsigned int m = ((const unsigned int*)msg)[(long)j * 64 + lane];
    ax += __uint_as_float(m << 16);            // col 2*lane
    ay += __uint_as_float(m & 0xFFFF0000u);    // col 2*lane+1
  }
  float2 o = ((float2*)out)[(long)n * 64 + lane];
  o.x += ax;
  o.y += ay;
  if (do_relu) { o.x = fmaxf(o.x, 0.f); o.y = fmaxf(o.y, 0.f); }
  ((float2*)out)[(long)n * 64 + lane] = o;
}

// ---------------------------------------------------------------------------
// Fallback (tiny ws): fp32 GEMM + atomic scatter + relu
// ---------------------------------------------------------------------------
__global__ __launch_bounds__(256) void edge_msg_atomic_kernel(
    const float* __restrict__ feat, const float* __restrict__ W,
    const float* __restrict__ norm, const int* __restrict__ src,
    const int* __restrict__ dst, float* __restrict__ out) {
  __shared__ float4 A4[64][32];
  __shared__ int s_src[64];
  __shared__ int s_dst[64];
  __shared__ float s_norm[64];
  int t = threadIdx.x;
  long base = (long)blockIdx.x * 64;
  int rel = blockIdx.x >> 8;
  const float4* Wr4 = (const float4*)(W + (long)rel * IN_FEAT * OUT_FEAT);

  if (t < 64) {
    s_src[t] = src[base + t];
    s_dst[t] = dst[base + t];
    s_norm[t] = norm[base + t];
  }
  __syncthreads();
#pragma unroll
  for (int j = 0; j < 8; ++j) {
    int idx = t + j * 256;
    int e = idx >> 5, k4 = idx & 31;
    A4[e][k4] = ((const float4*)feat)[(long)s_src[e] * 32 + k4];
  }
  __syncthreads();

  int og = t & 31, eg = t >> 5;
  float acc[8][4];
#pragma unroll
  for (int j = 0; j < 8; ++j)
#pragma unroll
    for (int d = 0; d < 4; ++d) acc[j][d] = 0.f;

  for (int k4 = 0; k4 < 32; ++k4) {
    float4 a[8];
#pragma unroll
    for (int j = 0; j < 8; ++j) a[j] = A4[eg * 8 + j][k4];
#pragma unroll
    for (int d = 0; d < 4; ++d) {
      float4 w = Wr4[(k4 * 4 + d) * 32 + og];
#pragma unroll
      for (int j = 0; j < 8; ++j) {
        float av = ((const float*)&a[j])[d];
        acc[j][0] += av * w.x;
        acc[j][1] += av * w.y;
        acc[j][2] += av * w.z;
        acc[j][3] += av * w.w;
      }
    }
  }
#pragma unroll
  for (int j = 0; j < 8; ++j) {
    int e = eg * 8 + j;
    float nm = s_norm[e];
    float* orow = out + (long)s_dst[e] * OUT_FEAT + og * 4;
#pragma unroll
    for (int d = 0; d < 4; ++d) atomicAdd(orow + d, acc[j][d] * nm);
  }
}

__global__ __launch_bounds__(256) void relu_kernel(float* __restrict__ out) {
  int idx = blockIdx.x * 256 + threadIdx.x;
  float4 v = ((const float4*)out)[idx];
  v.x = fmaxf(v.x, 0.f);
  v.y = fmaxf(v.y, 0.f);
  v.z = fmaxf(v.z, 0.f);
  v.w = fmaxf(v.w, 0.f);
  ((float4*)out)[idx] = v;
}

extern "C" void kernel_launch(void* const* d_in, const int* in_sizes, int n_in,
                              void* d_out, int out_size, void* d_ws, size_t ws_size,
                              hipStream_t stream) {
  const float* feat   = (const float*)d_in[0];
  const float* weight = (const float*)d_in[1];
  const float* w_comp = (const float*)d_in[2];
  const float* h_bias = (const float*)d_in[3];
  const float* loop_w = (const float*)d_in[4];
  const float* norm   = (const float*)d_in[5];
  const int*   src    = (const int*)d_in[6];
  const int*   dst    = (const int*)d_in[7];
  float* out = (float*)d_out;

  const size_t SZ_WP  = (size_t)NUM_RELS * IN_FEAT * OUT_FEAT * 2;  // 2 MB
  const size_t SZ_POS = (size_t)E_TOTAL * 4;                        // 4 MB

  // pick largest chunk size (in relations) that fits
  int CH = 0;
  {
    const int cands[5] = {64, 32, 16, 8, 4};
    for (int i = 0; i < 5 && CH == 0; ++i) {
      int ch = cands[i], nc = NUM_RELS / ch;
      size_t need = SZ_WP + SZ_POS + 2 * (size_t)nc * N_PAD * 4 +
                    2 * (size_t)nc * NBLK * 4 +
                    (size_t)ch * EDGES_PER_REL * OUT_FEAT * 2;
      if (ws_size >= need) CH = ch;
    }
  }

  hipLaunchKernelGGL(init_out_kernel, dim3((N_NODES + 63) / 64),
                     dim3(256), 0, stream, feat, loop_w, h_bias, out);

  if (CH > 0) {
    const int NC = NUM_RELS / CH;
    const int chunk_edges = CH * EDGES_PER_REL;
    int cshift = 14;
    for (int x = CH; x > 1; x >>= 1) ++cshift;   // log2(chunk_edges)

    char* p = (char*)d_ws;
    unsigned short* Wp = (unsigned short*)p;  p += SZ_WP;
    int* pos  = (int*)p;                      p += SZ_POS;
    int* cnt8 = (int*)p;                      p += (size_t)NC * N_PAD * 4;  // cnt -> fill
    int* row8 = (int*)p;                      p += (size_t)NC * N_PAD * 4;
    int* bsum = (int*)p;                      p += (size_t)NC * NBLK * 4;
    int* boff = (int*)p;                      p += (size_t)NC * NBLK * 4;
    unsigned short* msg = (unsigned short*)p;

    hipLaunchKernelGGL(compose_w_bf16_kernel, dim3(NUM_RELS * 16384 / 256),
                       dim3(256), 0, stream, weight, w_comp, Wp);
    hipLaunchKernelGGL(zero_kernel, dim3(NC * NBLK), dim3(256), 0, stream, cnt8);
    hipLaunchKernelGGL(hist8_kernel, dim3(E_TOTAL / 256), dim3(256), 0, stream,
                       dst, cnt8, cshift);
    hipLaunchKernelGGL(scan1_kernel, dim3(NC * NBLK), dim3(256), 0, stream,
                       cnt8, row8, bsum);
    hipLaunchKernelGGL(scan2_kernel, dim3(NC), dim3(512), 0, stream, bsum, boff);
    hipLaunchKernelGGL(scan3_kernel, dim3(NC * NBLK), dim3(256), 0, stream,
                       row8, boff, cnt8);
    hipLaunchKernelGGL(scatter_pos_kernel, dim3(E_TOTAL / 256), dim3(256), 0,
                       stream, dst, cnt8, pos, cshift);

    for (int c = 0; c < NC; ++c) {
      hipLaunchKernelGGL(edge_gemm_mfma, dim3(chunk_edges / 64), dim3(256), 0,
                         stream, feat, Wp, norm, src, pos, msg,
                         c * chunk_edges);
      hipLaunchKernelGGL(gather_csr_kernel, dim3((N_NODES + 3) / 4), dim3(256),
                         0, stream, msg, row8 + (size_t)c * N_PAD, out,
                         (c == NC - 1) ? 1 : 0);
    }
  } else {
    float* W = (float*)d_ws;    // 4 MB
    hipLaunchKernelGGL(compose_w_f32_kernel, dim3(NUM_RELS * 16384 / 256),
                       dim3(256), 0, stream, weight, w_comp, W);
    hipLaunchKernelGGL(edge_msg_atomic_kernel, dim3(E_TOTAL / 64), dim3(256), 0,
                       stream, feat, W, norm, src, dst, out);
    hipLaunchKernelGGL(relu_kernel, dim3((N_NODES * OUT_FEAT / 4) / 256),
                       dim3(256), 0, stream, out);
  }
}